// Round 8
// baseline (885.996 us; speedup 1.0000x reference)
//
#include <hip/hip_runtime.h>
#include <hip/hip_bf16.h>

#define F 128

typedef unsigned int uint;
typedef unsigned short ushort;
typedef __attribute__((ext_vector_type(8))) short short8;   // 8 bf16
typedef __attribute__((ext_vector_type(4))) float f32x4;

__device__ inline ushort f2bf(float f) {
    uint u = __float_as_uint(f);
    u += 0x7FFF + ((u >> 16) & 1);   // round-to-nearest-even
    return (ushort)(u >> 16);
}
__device__ inline float2 bf2f(uint u) {
    return make_float2(__uint_as_float(u << 16), __uint_as_float(u & 0xFFFF0000u));
}

// ---------------- CSR build ----------------
__global__ __launch_bounds__(256) void hist_kernel(const int* __restrict__ dst,
                                                   int* __restrict__ cnt, int E) {
    int e = blockIdx.x * 256 + threadIdx.x;
    if (e < E) atomicAdd(&cnt[dst[e]], 1);
}

__global__ __launch_bounds__(256) void scan_block(const int* __restrict__ cnt,
                                                  int* __restrict__ off,
                                                  int* __restrict__ bsum, int N) {
    __shared__ int t[256];
    int i = blockIdx.x * 256 + threadIdx.x;
    int v = (i < N) ? cnt[i] : 0;
    t[threadIdx.x] = v;
    __syncthreads();
    for (int o = 1; o < 256; o <<= 1) {
        int x = (threadIdx.x >= o) ? t[threadIdx.x - o] : 0;
        __syncthreads();
        t[threadIdx.x] += x;
        __syncthreads();
    }
    if (i < N) off[i] = t[threadIdx.x] - v;
    if (threadIdx.x == 255) bsum[blockIdx.x] = t[255];
}

__global__ __launch_bounds__(512) void scan_sums(int* __restrict__ bsum, int nb) {
    __shared__ int t[512];
    int v = (threadIdx.x < nb) ? bsum[threadIdx.x] : 0;
    t[threadIdx.x] = v;
    __syncthreads();
    for (int o = 1; o < 512; o <<= 1) {
        int x = (threadIdx.x >= o) ? t[threadIdx.x - o] : 0;
        __syncthreads();
        t[threadIdx.x] += x;
        __syncthreads();
    }
    if (threadIdx.x < nb) bsum[threadIdx.x] = t[threadIdx.x] - v;
}

// fused: finalize offsets, write cursor copy + rdeg (from cnt)
__global__ __launch_bounds__(256) void scan_add_rdeg(int* __restrict__ off,
                                                     const int* __restrict__ bsum,
                                                     const int* __restrict__ cnt,
                                                     int* __restrict__ cur,
                                                     float* __restrict__ rdeg, int N) {
    int i = blockIdx.x * 256 + threadIdx.x;
    if (i >= N) return;
    int o = off[i] + bsum[blockIdx.x];
    off[i] = o;
    cur[i] = o;
    rdeg[i] = 1.0f / fmaxf((float)cnt[i], 1.0f);
}

__global__ __launch_bounds__(256) void scatter_kernel(const int* __restrict__ src,
                                                      const int* __restrict__ dst,
                                                      int* __restrict__ cur,
                                                      int2* __restrict__ sE, int E) {
    int e = blockIdx.x * 256 + threadIdx.x;
    if (e >= E) return;
    int d = dst[e];
    int p = atomicAdd(&cur[d], 1);
    sE[p] = make_int2(src[e], e);
}

// ---------------- weight prep: cast + transpose 4 matrices [k][n] -> bf16 [n][k] ----------------
__global__ __launch_bounds__(256) void wprep(const float* __restrict__ W0,
                                             const float* __restrict__ W1,
                                             const float* __restrict__ W2,
                                             const float* __restrict__ W3,
                                             ushort* __restrict__ Wt) {
    int idx = blockIdx.x * 256 + threadIdx.x;   // 4 * 128*128
    if (idx >= 4 * 16384) return;
    int mat = idx >> 14;
    int pos = idx & 16383;
    int k = pos >> 7, n = pos & 127;
    const float* W = (mat == 0) ? W0 : (mat == 1) ? W1 : (mat == 2) ? W2 : W3;
    Wt[mat * 16384 + n * 128 + k] = f2bf(W[k * 128 + n]);
}

// ---------------- f32 -> bf16 cast (x only) ----------------
__global__ __launch_bounds__(256) void cast_bf16(const float* __restrict__ in,
                                                 uint* __restrict__ outb, int n4) {
    int i = blockIdx.x * 256 + threadIdx.x;
    if (i >= n4) return;
    float4 v = ((const float4*)in)[i];
    uint ua = (uint)f2bf(v.x) | ((uint)f2bf(v.y) << 16);
    uint ub = (uint)f2bf(v.z) | ((uint)f2bf(v.w) << 16);
    ((uint2*)outb)[i] = make_uint2(ua, ub);
}

// ---------------- fused SAGE layer: aggregate (gather) -> LDS -> MFMA ----------------
// Block = 256 thr = 4 waves = 64 node rows. Wave w owns rows w*16..w*16+15.
// Phase A: wave aggregates each of its 16 nodes (proven wave-per-node gather,
//          lane = feature pair, 4-edge unroll) into LDS bf16 rows (stride 65 uints).
// Phase B: MFMA; self A-frag from global h rows, neigh A-frag from LDS.
__global__ __launch_bounds__(256) void sage_fused(const uint* __restrict__ hb,
                                                  const int* __restrict__ off,
                                                  const int2* __restrict__ sE,
                                                  const float* __restrict__ rdeg,
                                                  const uint* __restrict__ Wt,
                                                  const float* __restrict__ bias,
                                                  ushort* __restrict__ outb, int N, int E) {
    __shared__ uint lds[4][16 * 65];
    int wave = threadIdx.x >> 6, lane = threadIdx.x & 63;
    int bn = blockIdx.x * 64 + wave * 16;

    // ---- Phase A: aggregate 16 nodes into LDS ----
    for (int n = 0; n < 16; n++) {
        int node = bn + n;
        float2 acc = make_float2(0.f, 0.f);
        if (node < N) {
            int p = off[node];
            int pe = (node == N - 1) ? E : off[node + 1];
            for (; p + 3 < pe; p += 4) {
                int s0 = sE[p].x, s1 = sE[p + 1].x, s2 = sE[p + 2].x, s3 = sE[p + 3].x;
                float2 f0 = bf2f(hb[(size_t)s0 * 64 + lane]);
                float2 f1 = bf2f(hb[(size_t)s1 * 64 + lane]);
                float2 f2 = bf2f(hb[(size_t)s2 * 64 + lane]);
                float2 f3 = bf2f(hb[(size_t)s3 * 64 + lane]);
                acc.x += (f0.x + f1.x) + (f2.x + f3.x);
                acc.y += (f0.y + f1.y) + (f2.y + f3.y);
            }
            for (; p < pe; ++p) {
                float2 f = bf2f(hb[(size_t)sE[p].x * 64 + lane]);
                acc.x += f.x;
                acc.y += f.y;
            }
            float rd = rdeg[node];
            acc.x *= rd;
            acc.y *= rd;
        }
        lds[wave][n * 65 + lane] = (uint)f2bf(acc.x) | ((uint)f2bf(acc.y) << 16);
    }

    // ---- Phase B: MFMA (wave-private LDS region; lgkmcnt hazard-tracked) ----
    int m = lane & 15, q = lane >> 4;
    int arow = bn + m;
    if (arow >= N) arow = N - 1;          // clamp; OOB A rows only feed discarded C rows

    f32x4 acc[8];
#pragma unroll
    for (int t = 0; t < 8; t++) acc[t] = (f32x4){0.f, 0.f, 0.f, 0.f};

    const uint* hrow = hb + (size_t)arow * 64;
    const uint* lrow = &lds[wave][m * 65];
#pragma unroll
    for (int sel = 0; sel < 2; sel++) {
        const uint* wsel = Wt + sel * 8192;
#pragma unroll
        for (int kk = 0; kk < 4; kk++) {
            int ko = kk * 16 + q * 4;
            short8 a;
            if (sel == 0) a = *(const short8*)(hrow + ko);
            else          a = *(const short8*)(lrow + ko);
#pragma unroll
            for (int t = 0; t < 8; t++) {
                short8 b = *(const short8*)(wsel + (size_t)(16 * t + m) * 64 + ko);
                acc[t] = __builtin_amdgcn_mfma_f32_16x16x32_bf16(a, b, acc[t], 0, 0, 0);
            }
        }
    }

#pragma unroll
    for (int t = 0; t < 8; t++) {
        float bs = bias[16 * t + m];
#pragma unroll
        for (int r = 0; r < 4; r++) {
            int orow = bn + q * 4 + r;
            if (orow < N) outb[(size_t)orow * 128 + 16 * t + m] = f2bf(acc[t][r] + bs);
        }
    }
}

// ---------------- edge score + per-block min/max partials (non-atomic) ----------------
__global__ __launch_bounds__(256) void edge_score_csr(const uint* __restrict__ hb,
                                                      const int* __restrict__ off,
                                                      const int2* __restrict__ sE,
                                                      float* __restrict__ s,
                                                      float2* __restrict__ pmm, int N, int E) {
    int node = blockIdx.x * 4 + (threadIdx.x >> 6);
    int lane = threadIdx.x & 63;
    float lmin = INFINITY, lmax = -INFINITY;

    if (node < N) {
        int p = off[node];
        int pe = (node == N - 1) ? E : off[node + 1];
        if (p < pe) {
            float2 d = bf2f(hb[(size_t)node * 64 + lane]);
            for (; p + 3 < pe; p += 4) {
                int2 se0 = sE[p], se1 = sE[p + 1], se2 = sE[p + 2], se3 = sE[p + 3];
                float2 a0 = bf2f(hb[(size_t)se0.x * 64 + lane]);
                float2 a1 = bf2f(hb[(size_t)se1.x * 64 + lane]);
                float2 a2 = bf2f(hb[(size_t)se2.x * 64 + lane]);
                float2 a3 = bf2f(hb[(size_t)se3.x * 64 + lane]);
                float v0 = a0.x * d.x + a0.y * d.y;
                float v1 = a1.x * d.x + a1.y * d.y;
                float v2 = a2.x * d.x + a2.y * d.y;
                float v3 = a3.x * d.x + a3.y * d.y;
#pragma unroll
                for (int o = 32; o > 0; o >>= 1) {
                    v0 += __shfl_down(v0, o);
                    v1 += __shfl_down(v1, o);
                    v2 += __shfl_down(v2, o);
                    v3 += __shfl_down(v3, o);
                }
                if (lane == 0) {
                    s[se0.y] = v0; s[se1.y] = v1; s[se2.y] = v2; s[se3.y] = v3;
                    lmin = fminf(lmin, fminf(fminf(v0, v1), fminf(v2, v3)));
                    lmax = fmaxf(lmax, fmaxf(fmaxf(v0, v1), fmaxf(v2, v3)));
                }
            }
            for (; p < pe; ++p) {
                int2 se = sE[p];
                float2 a = bf2f(hb[(size_t)se.x * 64 + lane]);
                float v = a.x * d.x + a.y * d.y;
#pragma unroll
                for (int o = 32; o > 0; o >>= 1) v += __shfl_down(v, o);
                if (lane == 0) {
                    s[se.y] = v;
                    lmin = fminf(lmin, v);
                    lmax = fmaxf(lmax, v);
                }
            }
        }
    }

#pragma unroll
    for (int o = 1; o <= 32; o <<= 1) {
        lmin = fminf(lmin, __shfl_xor(lmin, o));
        lmax = fmaxf(lmax, __shfl_xor(lmax, o));
    }
    __shared__ float smin[4], smax[4];
    int wv = threadIdx.x >> 6;
    if (lane == 0) { smin[wv] = lmin; smax[wv] = lmax; }
    __syncthreads();
    if (threadIdx.x == 0) {
        float m = fminf(fminf(smin[0], smin[1]), fminf(smin[2], smin[3]));
        float M = fmaxf(fmaxf(smax[0], smax[1]), fmaxf(smax[2], smax[3]));
        pmm[blockIdx.x] = make_float2(m, M);
    }
}

__global__ __launch_bounds__(1024) void minmax_final(const float2* __restrict__ pmm,
                                                     float* __restrict__ mmf, int nb) {
    float vmin = INFINITY, vmax = -INFINITY;
    for (int i = threadIdx.x; i < nb; i += 1024) {
        float2 v = pmm[i];
        vmin = fminf(vmin, v.x);
        vmax = fmaxf(vmax, v.y);
    }
#pragma unroll
    for (int o = 1; o <= 32; o <<= 1) {
        vmin = fminf(vmin, __shfl_xor(vmin, o));
        vmax = fmaxf(vmax, __shfl_xor(vmax, o));
    }
    __shared__ float smin[16], smax[16];
    int lane = threadIdx.x & 63, wv = threadIdx.x >> 6;
    if (lane == 0) { smin[wv] = vmin; smax[wv] = vmax; }
    __syncthreads();
    if (threadIdx.x == 0) {
        float m = smin[0], M = smax[0];
        for (int w = 1; w < 16; w++) { m = fminf(m, smin[w]); M = fmaxf(M, smax[w]); }
        mmf[0] = m;
        mmf[1] = M;
    }
}

__global__ __launch_bounds__(256) void norm_kernel(float* __restrict__ s,
                                                   const float* __restrict__ mmf, int E) {
    float mn = mmf[0];
    float mx = mmf[1];
    float inv = 1.0f / (mx - mn);
    int i = blockIdx.x * 256 + threadIdx.x;
    if (i < E) s[i] = (s[i] - mn) * inv;
}

extern "C" void kernel_launch(void* const* d_in, const int* in_sizes, int n_in,
                              void* d_out, int out_size, void* d_ws, size_t ws_size,
                              hipStream_t stream) {
    const float* x   = (const float*)d_in[0];
    const int*   src = (const int*)d_in[1];
    const int*   dst = (const int*)d_in[2];
    const float* Ws1 = (const float*)d_in[3];
    const float* Wn1 = (const float*)d_in[4];
    const float* b1  = (const float*)d_in[5];
    const float* Ws2 = (const float*)d_in[6];
    const float* Wn2 = (const float*)d_in[7];
    const float* b2  = (const float*)d_in[8];

    int N = in_sizes[0] / F;   // 100000
    int E = in_sizes[1];       // 1600000
    float* out = (float*)d_out;

    int nbN = (N + 255) / 256;
    int nbE = (E + 255) / 256;
    int nbEdgeBlocks = (N + 3) / 4;       // edge_score grid (25000)
    int NF4 = N * F / 4;

    // workspace layout (4-byte elements)
    int* off  = (int*)d_ws;                  // N
    int* cur  = off + N;                     // N
    int* cnt  = cur + N;                     // N (hist output, kept for rdeg)
    int2* sE  = (int2*)(cnt + N);            // E int2 (2E words)
    int* bsum = (int*)(sE + E);              // 1024
    float* rdeg = (float*)(bsum + 1024);     // N
    float* mmf = (float*)(rdeg + N);         // 2 (+2 pad)
    float2* pmm = (float2*)(mmf + 4);        // nbEdgeBlocks float2 (pad to 25600)
    uint* Wtb = (uint*)(pmm + 25600);        // 4*16384 bf16 = 32768 uints
    size_t elemOff = 4 * (size_t)N + 2 * (size_t)E + 1024 + 4 + 51200 + 32768;
    elemOff = (elemOff + 3) & ~(size_t)3;    // 16B align
    uint* xb   = (uint*)d_ws + elemOff;      // N*64
    uint* h1b  = xb + (size_t)N * 64;        // N*64
    uint* h2b  = h1b + (size_t)N * 64;       // N*64

    // init
    hipMemsetAsync(cnt, 0, (size_t)N * sizeof(int), stream);

    // CSR build (by dst)
    hist_kernel<<<nbE, 256, 0, stream>>>(dst, cnt, E);
    scan_block<<<nbN, 256, 0, stream>>>(cnt, off, bsum, N);
    scan_sums<<<1, 512, 0, stream>>>(bsum, nbN);
    scan_add_rdeg<<<nbN, 256, 0, stream>>>(off, bsum, cnt, cur, rdeg, N);
    scatter_kernel<<<nbE, 256, 0, stream>>>(src, dst, cur, sE, E);

    // weights + input cast
    wprep<<<256, 256, 0, stream>>>(Ws1, Wn1, Ws2, Wn2, (ushort*)Wtb);
    cast_bf16<<<(NF4 + 255) / 256, 256, 0, stream>>>(x, xb, NF4);

    // layer 1 + layer 2 (fused aggregate + MFMA)
    sage_fused<<<(N + 63) / 64, 256, 0, stream>>>(xb, off, sE, rdeg, Wtb, b1,
                                                  (ushort*)h1b, N, E);
    sage_fused<<<(N + 63) / 64, 256, 0, stream>>>(h1b, off, sE, rdeg, Wtb + 16384, b2,
                                                  (ushort*)h2b, N, E);

    // edge scores (+ per-block min/max partials) + final reduce + normalize
    edge_score_csr<<<nbEdgeBlocks, 256, 0, stream>>>(h2b, off, sE, out, pmm, N, E);
    minmax_final<<<1, 1024, 0, stream>>>(pmm, mmf, nbEdgeBlocks);
    norm_kernel<<<(E + 255) / 256, 256, 0, stream>>>(out, mmf, E);
}

// Round 9
// 776.147 us; speedup vs baseline: 1.1415x; 1.1415x over previous
//
#include <hip/hip_runtime.h>
#include <hip/hip_bf16.h>

#define F 128

typedef unsigned int uint;
typedef unsigned short ushort;
typedef __attribute__((ext_vector_type(8))) short short8;   // 8 bf16
typedef __attribute__((ext_vector_type(4))) float f32x4;

__device__ inline ushort f2bf(float f) {
    uint u = __float_as_uint(f);
    u += 0x7FFF + ((u >> 16) & 1);   // round-to-nearest-even
    return (ushort)(u >> 16);
}
__device__ inline float2 bf2f(uint u) {
    return make_float2(__uint_as_float(u << 16), __uint_as_float(u & 0xFFFF0000u));
}

// ---------------- CSR build ----------------
__global__ __launch_bounds__(256) void hist_kernel(const int* __restrict__ dst,
                                                   int* __restrict__ cnt, int E) {
    int e = blockIdx.x * 256 + threadIdx.x;
    if (e < E) atomicAdd(&cnt[dst[e]], 1);
}

__global__ __launch_bounds__(256) void scan_block(const int* __restrict__ cnt,
                                                  int* __restrict__ off,
                                                  int* __restrict__ bsum, int N) {
    __shared__ int t[256];
    int i = blockIdx.x * 256 + threadIdx.x;
    int v = (i < N) ? cnt[i] : 0;
    t[threadIdx.x] = v;
    __syncthreads();
    for (int o = 1; o < 256; o <<= 1) {
        int x = (threadIdx.x >= o) ? t[threadIdx.x - o] : 0;
        __syncthreads();
        t[threadIdx.x] += x;
        __syncthreads();
    }
    if (i < N) off[i] = t[threadIdx.x] - v;
    if (threadIdx.x == 255) bsum[blockIdx.x] = t[255];
}

__global__ __launch_bounds__(512) void scan_sums(int* __restrict__ bsum, int nb) {
    __shared__ int t[512];
    int v = (threadIdx.x < nb) ? bsum[threadIdx.x] : 0;
    t[threadIdx.x] = v;
    __syncthreads();
    for (int o = 1; o < 512; o <<= 1) {
        int x = (threadIdx.x >= o) ? t[threadIdx.x - o] : 0;
        __syncthreads();
        t[threadIdx.x] += x;
        __syncthreads();
    }
    if (threadIdx.x < nb) bsum[threadIdx.x] = t[threadIdx.x] - v;
}

// fused: finalize offsets, write cursor copy + rdeg (from cnt)
__global__ __launch_bounds__(256) void scan_add_rdeg(int* __restrict__ off,
                                                     const int* __restrict__ bsum,
                                                     const int* __restrict__ cnt,
                                                     int* __restrict__ cur,
                                                     float* __restrict__ rdeg, int N) {
    int i = blockIdx.x * 256 + threadIdx.x;
    if (i >= N) return;
    int o = off[i] + bsum[blockIdx.x];
    off[i] = o;
    cur[i] = o;
    rdeg[i] = 1.0f / fmaxf((float)cnt[i], 1.0f);
}

// scatter: 4B random store (srcS) + sequential rank store
__global__ __launch_bounds__(256) void scatter_kernel(const int* __restrict__ src,
                                                      const int* __restrict__ dst,
                                                      int* __restrict__ cur,
                                                      int* __restrict__ srcS,
                                                      int* __restrict__ rank, int E) {
    int e = blockIdx.x * 256 + threadIdx.x;
    if (e >= E) return;
    int d = dst[e];
    int p = atomicAdd(&cur[d], 1);
    srcS[p] = src[e];
    rank[e] = p;
}

// ---------------- weight prep: cast + transpose 4 matrices [k][n] -> bf16 [n][k] ----------------
__global__ __launch_bounds__(256) void wprep(const float* __restrict__ W0,
                                             const float* __restrict__ W1,
                                             const float* __restrict__ W2,
                                             const float* __restrict__ W3,
                                             ushort* __restrict__ Wt) {
    int idx = blockIdx.x * 256 + threadIdx.x;   // 4 * 128*128
    if (idx >= 4 * 16384) return;
    int mat = idx >> 14;
    int pos = idx & 16383;
    int k = pos >> 7, n = pos & 127;
    const float* W = (mat == 0) ? W0 : (mat == 1) ? W1 : (mat == 2) ? W2 : W3;
    Wt[mat * 16384 + n * 128 + k] = f2bf(W[k * 128 + n]);
}

// ---------------- f32 -> bf16 cast (x only) ----------------
__global__ __launch_bounds__(256) void cast_bf16(const float* __restrict__ in,
                                                 uint* __restrict__ outb, int n4) {
    int i = blockIdx.x * 256 + threadIdx.x;
    if (i >= n4) return;
    float4 v = ((const float4*)in)[i];
    uint ua = (uint)f2bf(v.x) | ((uint)f2bf(v.y) << 16);
    uint ub = (uint)f2bf(v.z) | ((uint)f2bf(v.w) << 16);
    ((uint2*)outb)[i] = make_uint2(ua, ub);
}

// ---------------- aggregate (gather, unroll 8): msg[n] = mean h[srcs] ----------------
// wave per node, lane = feature pair; p wave-uniform -> coalesced row loads.
__global__ __launch_bounds__(256) void agg_gather(const uint* __restrict__ hb,
                                                  const int* __restrict__ off,
                                                  const int* __restrict__ srcS,
                                                  const float* __restrict__ rdeg,
                                                  uint* __restrict__ msgb, int N, int E) {
    int node = blockIdx.x * 4 + (threadIdx.x >> 6);
    int lane = threadIdx.x & 63;
    if (node >= N) return;
    int p = off[node];
    int pe = (node == N - 1) ? E : off[node + 1];
    float2 acc = make_float2(0.f, 0.f);
    for (; p + 7 < pe; p += 8) {
        int s0 = srcS[p],     s1 = srcS[p + 1], s2 = srcS[p + 2], s3 = srcS[p + 3];
        int s4 = srcS[p + 4], s5 = srcS[p + 5], s6 = srcS[p + 6], s7 = srcS[p + 7];
        float2 f0 = bf2f(hb[(size_t)s0 * 64 + lane]);
        float2 f1 = bf2f(hb[(size_t)s1 * 64 + lane]);
        float2 f2 = bf2f(hb[(size_t)s2 * 64 + lane]);
        float2 f3 = bf2f(hb[(size_t)s3 * 64 + lane]);
        float2 f4 = bf2f(hb[(size_t)s4 * 64 + lane]);
        float2 f5 = bf2f(hb[(size_t)s5 * 64 + lane]);
        float2 f6 = bf2f(hb[(size_t)s6 * 64 + lane]);
        float2 f7 = bf2f(hb[(size_t)s7 * 64 + lane]);
        acc.x += ((f0.x + f1.x) + (f2.x + f3.x)) + ((f4.x + f5.x) + (f6.x + f7.x));
        acc.y += ((f0.y + f1.y) + (f2.y + f3.y)) + ((f4.y + f5.y) + (f6.y + f7.y));
    }
    for (; p < pe; ++p) {
        float2 f = bf2f(hb[(size_t)srcS[p] * 64 + lane]);
        acc.x += f.x;
        acc.y += f.y;
    }
    float rd = rdeg[node];
    msgb[(size_t)node * 64 + lane] = (uint)f2bf(acc.x * rd) | ((uint)f2bf(acc.y * rd) << 16);
}

// ---------------- SAGE layer via MFMA ----------------
__global__ __launch_bounds__(256) void sage_mfma(const uint* __restrict__ hb,
                                                 const uint* __restrict__ mb,
                                                 const uint* __restrict__ Wt,
                                                 const float* __restrict__ bias,
                                                 ushort* __restrict__ outb, int N) {
    int wave = threadIdx.x >> 6, lane = threadIdx.x & 63;
    int m = lane & 15, q = lane >> 4;
    int r0 = blockIdx.x * 64 + wave * 16;
    int arow = r0 + m;
    if (arow >= N) arow = N - 1;

    f32x4 acc[8];
#pragma unroll
    for (int t = 0; t < 8; t++) acc[t] = (f32x4){0.f, 0.f, 0.f, 0.f};

    const uint* hrow = hb + (size_t)arow * 64;
    const uint* mrow = mb + (size_t)arow * 64;
#pragma unroll
    for (int sel = 0; sel < 2; sel++) {
        const uint* arowp = sel ? mrow : hrow;
        const uint* wsel = Wt + sel * 8192;
#pragma unroll
        for (int kk = 0; kk < 4; kk++) {
            int ko = kk * 16 + q * 4;
            short8 a = *(const short8*)(arowp + ko);
#pragma unroll
            for (int t = 0; t < 8; t++) {
                short8 b = *(const short8*)(wsel + (size_t)(16 * t + m) * 64 + ko);
                acc[t] = __builtin_amdgcn_mfma_f32_16x16x32_bf16(a, b, acc[t], 0, 0, 0);
            }
        }
    }

#pragma unroll
    for (int t = 0; t < 8; t++) {
        float bs = bias[16 * t + m];
#pragma unroll
        for (int r = 0; r < 4; r++) {
            int orow = r0 + q * 4 + r;
            if (orow < N) outb[(size_t)orow * 128 + 16 * t + m] = f2bf(acc[t][r] + bs);
        }
    }
}

// ---------------- edge score (unroll 8, sequential CSR-order stores, fused partials) ----------------
__global__ __launch_bounds__(256) void edge_score_csr(const uint* __restrict__ hb,
                                                      const int* __restrict__ off,
                                                      const int* __restrict__ srcS,
                                                      float* __restrict__ sc,
                                                      float2* __restrict__ pmm, int N, int E) {
    int node = blockIdx.x * 4 + (threadIdx.x >> 6);
    int lane = threadIdx.x & 63;
    float lmin = INFINITY, lmax = -INFINITY;

    if (node < N) {
        int p = off[node];
        int pe = (node == N - 1) ? E : off[node + 1];
        if (p < pe) {
            float2 d = bf2f(hb[(size_t)node * 64 + lane]);
            for (; p + 7 < pe; p += 8) {
                int s0 = srcS[p],     s1 = srcS[p + 1], s2 = srcS[p + 2], s3 = srcS[p + 3];
                int s4 = srcS[p + 4], s5 = srcS[p + 5], s6 = srcS[p + 6], s7 = srcS[p + 7];
                float2 a0 = bf2f(hb[(size_t)s0 * 64 + lane]);
                float2 a1 = bf2f(hb[(size_t)s1 * 64 + lane]);
                float2 a2 = bf2f(hb[(size_t)s2 * 64 + lane]);
                float2 a3 = bf2f(hb[(size_t)s3 * 64 + lane]);
                float2 a4 = bf2f(hb[(size_t)s4 * 64 + lane]);
                float2 a5 = bf2f(hb[(size_t)s5 * 64 + lane]);
                float2 a6 = bf2f(hb[(size_t)s6 * 64 + lane]);
                float2 a7 = bf2f(hb[(size_t)s7 * 64 + lane]);
                float v0 = a0.x * d.x + a0.y * d.y;
                float v1 = a1.x * d.x + a1.y * d.y;
                float v2 = a2.x * d.x + a2.y * d.y;
                float v3 = a3.x * d.x + a3.y * d.y;
                float v4 = a4.x * d.x + a4.y * d.y;
                float v5 = a5.x * d.x + a5.y * d.y;
                float v6 = a6.x * d.x + a6.y * d.y;
                float v7 = a7.x * d.x + a7.y * d.y;
#pragma unroll
                for (int o = 32; o > 0; o >>= 1) {
                    v0 += __shfl_down(v0, o);
                    v1 += __shfl_down(v1, o);
                    v2 += __shfl_down(v2, o);
                    v3 += __shfl_down(v3, o);
                    v4 += __shfl_down(v4, o);
                    v5 += __shfl_down(v5, o);
                    v6 += __shfl_down(v6, o);
                    v7 += __shfl_down(v7, o);
                }
                if (lane == 0) {
                    sc[p] = v0; sc[p + 1] = v1; sc[p + 2] = v2; sc[p + 3] = v3;
                    sc[p + 4] = v4; sc[p + 5] = v5; sc[p + 6] = v6; sc[p + 7] = v7;
                    float mn = fminf(fminf(fminf(v0, v1), fminf(v2, v3)),
                                     fminf(fminf(v4, v5), fminf(v6, v7)));
                    float mx = fmaxf(fmaxf(fmaxf(v0, v1), fmaxf(v2, v3)),
                                     fmaxf(fmaxf(v4, v5), fmaxf(v6, v7)));
                    lmin = fminf(lmin, mn);
                    lmax = fmaxf(lmax, mx);
                }
            }
            for (; p < pe; ++p) {
                float2 a = bf2f(hb[(size_t)srcS[p] * 64 + lane]);
                float v = a.x * d.x + a.y * d.y;
#pragma unroll
                for (int o = 32; o > 0; o >>= 1) v += __shfl_down(v, o);
                if (lane == 0) {
                    sc[p] = v;
                    lmin = fminf(lmin, v);
                    lmax = fmaxf(lmax, v);
                }
            }
        }
    }

#pragma unroll
    for (int o = 1; o <= 32; o <<= 1) {
        lmin = fminf(lmin, __shfl_xor(lmin, o));
        lmax = fmaxf(lmax, __shfl_xor(lmax, o));
    }
    __shared__ float smin[4], smax[4];
    int wv = threadIdx.x >> 6;
    if (lane == 0) { smin[wv] = lmin; smax[wv] = lmax; }
    __syncthreads();
    if (threadIdx.x == 0) {
        float m = fminf(fminf(smin[0], smin[1]), fminf(smin[2], smin[3]));
        float M = fmaxf(fmaxf(smax[0], smax[1]), fmaxf(smax[2], smax[3]));
        pmm[blockIdx.x] = make_float2(m, M);
    }
}

__global__ __launch_bounds__(1024) void minmax_final(const float2* __restrict__ pmm,
                                                     float* __restrict__ mmf, int nb) {
    float vmin = INFINITY, vmax = -INFINITY;
    for (int i = threadIdx.x; i < nb; i += 1024) {
        float2 v = pmm[i];
        vmin = fminf(vmin, v.x);
        vmax = fmaxf(vmax, v.y);
    }
#pragma unroll
    for (int o = 1; o <= 32; o <<= 1) {
        vmin = fminf(vmin, __shfl_xor(vmin, o));
        vmax = fmaxf(vmax, __shfl_xor(vmax, o));
    }
    __shared__ float smin[16], smax[16];
    int lane = threadIdx.x & 63, wv = threadIdx.x >> 6;
    if (lane == 0) { smin[wv] = vmin; smax[wv] = vmax; }
    __syncthreads();
    if (threadIdx.x == 0) {
        float m = smin[0], M = smax[0];
        for (int w = 1; w < 16; w++) { m = fminf(m, smin[w]); M = fmaxf(M, smax[w]); }
        mmf[0] = m;
        mmf[1] = M;
    }
}

// out[e] = (sc[rank[e]] - mn) * inv   (sequential read of rank, L2 gather of sc)
__global__ __launch_bounds__(256) void norm_kernel(const float* __restrict__ sc,
                                                   const int* __restrict__ rank,
                                                   float* __restrict__ out,
                                                   const float* __restrict__ mmf, int E) {
    float mn = mmf[0];
    float mx = mmf[1];
    float inv = 1.0f / (mx - mn);
    int i = blockIdx.x * 256 + threadIdx.x;
    if (i < E) out[i] = (sc[rank[i]] - mn) * inv;
}

extern "C" void kernel_launch(void* const* d_in, const int* in_sizes, int n_in,
                              void* d_out, int out_size, void* d_ws, size_t ws_size,
                              hipStream_t stream) {
    const float* x   = (const float*)d_in[0];
    const int*   src = (const int*)d_in[1];
    const int*   dst = (const int*)d_in[2];
    const float* Ws1 = (const float*)d_in[3];
    const float* Wn1 = (const float*)d_in[4];
    const float* b1  = (const float*)d_in[5];
    const float* Ws2 = (const float*)d_in[6];
    const float* Wn2 = (const float*)d_in[7];
    const float* b2  = (const float*)d_in[8];

    int N = in_sizes[0] / F;   // 100000
    int E = in_sizes[1];       // 1600000
    float* out = (float*)d_out;

    int nbN = (N + 255) / 256;
    int nbE = (E + 255) / 256;
    int nbEdgeBlocks = (N + 3) / 4;       // 25000
    int NF4 = N * F / 4;

    // workspace layout (4-byte elements)
    int* off  = (int*)d_ws;                  // N
    int* cur  = off + N;                     // N
    int* cnt  = cur + N;                     // N
    int* srcS = cnt + N;                     // E
    int* rank = srcS + E;                    // E
    float* sc = (float*)(rank + E);          // E (scores in CSR order)
    int* bsum = (int*)(sc + E);              // 1024
    float* rdeg = (float*)(bsum + 1024);     // N
    float* mmf = (float*)(rdeg + N);         // 2 (+2 pad)
    float2* pmm = (float2*)(mmf + 4);        // 25600 float2
    uint* Wtb = (uint*)(pmm + 25600);        // 32768 uints
    size_t elemOff = 4 * (size_t)N + 3 * (size_t)E + 1024 + 4 + 51200 + 32768;
    elemOff = (elemOff + 3) & ~(size_t)3;    // 16B align
    uint* xb   = (uint*)d_ws + elemOff;      // N*64
    uint* msgb = xb + (size_t)N * 64;        // N*64
    uint* h1b  = msgb + (size_t)N * 64;      // N*64
    uint* h2b  = h1b + (size_t)N * 64;       // N*64

    // init
    hipMemsetAsync(cnt, 0, (size_t)N * sizeof(int), stream);

    // CSR build (by dst)
    hist_kernel<<<nbE, 256, 0, stream>>>(dst, cnt, E);
    scan_block<<<nbN, 256, 0, stream>>>(cnt, off, bsum, N);
    scan_sums<<<1, 512, 0, stream>>>(bsum, nbN);
    scan_add_rdeg<<<nbN, 256, 0, stream>>>(off, bsum, cnt, cur, rdeg, N);
    scatter_kernel<<<nbE, 256, 0, stream>>>(src, dst, cur, srcS, rank, E);

    // weights + input cast
    wprep<<<256, 256, 0, stream>>>(Ws1, Wn1, Ws2, Wn2, (ushort*)Wtb);
    cast_bf16<<<(NF4 + 255) / 256, 256, 0, stream>>>(x, xb, NF4);

    // layer 1
    agg_gather<<<(N + 3) / 4, 256, 0, stream>>>(xb, off, srcS, rdeg, msgb, N, E);
    sage_mfma<<<(N + 63) / 64, 256, 0, stream>>>(xb, msgb, Wtb, b1, (ushort*)h1b, N);

    // layer 2
    agg_gather<<<(N + 3) / 4, 256, 0, stream>>>(h1b, off, srcS, rdeg, msgb, N, E);
    sage_mfma<<<(N + 63) / 64, 256, 0, stream>>>(h1b, msgb, Wtb + 16384, b2, (ushort*)h2b, N);

    // edge scores (CSR order + per-block partials) + final reduce + permute-normalize
    edge_score_csr<<<nbEdgeBlocks, 256, 0, stream>>>(h2b, off, srcS, sc, pmm, N, E);
    minmax_final<<<1, 1024, 0, stream>>>(pmm, mmf, nbEdgeBlocks);
    norm_kernel<<<(E + 255) / 256, 256, 0, stream>>>(sc, rank, out, mmf, E);
}

// Round 10
// 677.895 us; speedup vs baseline: 1.3070x; 1.1449x over previous
//
#include <hip/hip_runtime.h>
#include <hip/hip_bf16.h>

#define F 128

typedef unsigned int uint;
typedef unsigned short ushort;
typedef __attribute__((ext_vector_type(8))) short short8;   // 8 bf16
typedef __attribute__((ext_vector_type(4))) float f32x4;

__device__ inline ushort f2bf(float f) {
    uint u = __float_as_uint(f);
    u += 0x7FFF + ((u >> 16) & 1);   // round-to-nearest-even
    return (ushort)(u >> 16);
}
__device__ inline float2 bf2f(uint u) {
    return make_float2(__uint_as_float(u << 16), __uint_as_float(u & 0xFFFF0000u));
}

// ---------------- CSR build ----------------
// pass 1: histogram + per-edge relative rank within its dst bucket (ONE atomic pass)
__global__ __launch_bounds__(256) void rank_kernel(const int* __restrict__ dst,
                                                   int* __restrict__ cnt,
                                                   ushort* __restrict__ rel, int E) {
    int e = blockIdx.x * 256 + threadIdx.x;
    if (e < E) rel[e] = (ushort)atomicAdd(&cnt[dst[e]], 1);
}

__global__ __launch_bounds__(256) void scan_block(const int* __restrict__ cnt,
                                                  int* __restrict__ off,
                                                  int* __restrict__ bsum, int N) {
    __shared__ int t[256];
    int i = blockIdx.x * 256 + threadIdx.x;
    int v = (i < N) ? cnt[i] : 0;
    t[threadIdx.x] = v;
    __syncthreads();
    for (int o = 1; o < 256; o <<= 1) {
        int x = (threadIdx.x >= o) ? t[threadIdx.x - o] : 0;
        __syncthreads();
        t[threadIdx.x] += x;
        __syncthreads();
    }
    if (i < N) off[i] = t[threadIdx.x] - v;
    if (threadIdx.x == 255) bsum[blockIdx.x] = t[255];
}

__global__ __launch_bounds__(512) void scan_sums(int* __restrict__ bsum, int nb) {
    __shared__ int t[512];
    int v = (threadIdx.x < nb) ? bsum[threadIdx.x] : 0;
    t[threadIdx.x] = v;
    __syncthreads();
    for (int o = 1; o < 512; o <<= 1) {
        int x = (threadIdx.x >= o) ? t[threadIdx.x - o] : 0;
        __syncthreads();
        t[threadIdx.x] += x;
        __syncthreads();
    }
    if (threadIdx.x < nb) bsum[threadIdx.x] = t[threadIdx.x] - v;
}

// finalize offsets + rdeg (no cursor needed anymore)
__global__ __launch_bounds__(256) void scan_add_rdeg(int* __restrict__ off,
                                                     const int* __restrict__ bsum,
                                                     const int* __restrict__ cnt,
                                                     float* __restrict__ rdeg, int N) {
    int i = blockIdx.x * 256 + threadIdx.x;
    if (i >= N) return;
    off[i] += bsum[blockIdx.x];
    rdeg[i] = 1.0f / fmaxf((float)cnt[i], 1.0f);
}

// pass 2: atomic-free fill. p derived from scan + relative rank.
__global__ __launch_bounds__(256) void fill_kernel(const int* __restrict__ src,
                                                   const int* __restrict__ dst,
                                                   const int* __restrict__ off,
                                                   const ushort* __restrict__ rel,
                                                   int* __restrict__ srcS,
                                                   int* __restrict__ rank, int E) {
    int e = blockIdx.x * 256 + threadIdx.x;
    if (e >= E) return;
    int p = off[dst[e]] + (int)rel[e];
    srcS[p] = src[e];
    rank[e] = p;
}

// ---------------- weight prep: cast + transpose 4 matrices [k][n] -> bf16 [n][k] ----------------
__global__ __launch_bounds__(256) void wprep(const float* __restrict__ W0,
                                             const float* __restrict__ W1,
                                             const float* __restrict__ W2,
                                             const float* __restrict__ W3,
                                             ushort* __restrict__ Wt) {
    int idx = blockIdx.x * 256 + threadIdx.x;   // 4 * 128*128
    if (idx >= 4 * 16384) return;
    int mat = idx >> 14;
    int pos = idx & 16383;
    int k = pos >> 7, n = pos & 127;
    const float* W = (mat == 0) ? W0 : (mat == 1) ? W1 : (mat == 2) ? W2 : W3;
    Wt[mat * 16384 + n * 128 + k] = f2bf(W[k * 128 + n]);
}

// ---------------- f32 -> bf16 cast (x only) ----------------
__global__ __launch_bounds__(256) void cast_bf16(const float* __restrict__ in,
                                                 uint* __restrict__ outb, int n4) {
    int i = blockIdx.x * 256 + threadIdx.x;
    if (i >= n4) return;
    float4 v = ((const float4*)in)[i];
    uint ua = (uint)f2bf(v.x) | ((uint)f2bf(v.y) << 16);
    uint ub = (uint)f2bf(v.z) | ((uint)f2bf(v.w) << 16);
    ((uint2*)outb)[i] = make_uint2(ua, ub);
}

// ---------------- aggregate (gather, unroll 8): msg[n] = mean h[srcs] ----------------
// wave per node, lane = feature pair; p wave-uniform -> coalesced row loads.
__global__ __launch_bounds__(256) void agg_gather(const uint* __restrict__ hb,
                                                  const int* __restrict__ off,
                                                  const int* __restrict__ srcS,
                                                  const float* __restrict__ rdeg,
                                                  uint* __restrict__ msgb, int N, int E) {
    int node = blockIdx.x * 4 + (threadIdx.x >> 6);
    int lane = threadIdx.x & 63;
    if (node >= N) return;
    int p = off[node];
    int pe = (node == N - 1) ? E : off[node + 1];
    float2 acc = make_float2(0.f, 0.f);
    for (; p + 7 < pe; p += 8) {
        int s0 = srcS[p],     s1 = srcS[p + 1], s2 = srcS[p + 2], s3 = srcS[p + 3];
        int s4 = srcS[p + 4], s5 = srcS[p + 5], s6 = srcS[p + 6], s7 = srcS[p + 7];
        float2 f0 = bf2f(hb[(size_t)s0 * 64 + lane]);
        float2 f1 = bf2f(hb[(size_t)s1 * 64 + lane]);
        float2 f2 = bf2f(hb[(size_t)s2 * 64 + lane]);
        float2 f3 = bf2f(hb[(size_t)s3 * 64 + lane]);
        float2 f4 = bf2f(hb[(size_t)s4 * 64 + lane]);
        float2 f5 = bf2f(hb[(size_t)s5 * 64 + lane]);
        float2 f6 = bf2f(hb[(size_t)s6 * 64 + lane]);
        float2 f7 = bf2f(hb[(size_t)s7 * 64 + lane]);
        acc.x += ((f0.x + f1.x) + (f2.x + f3.x)) + ((f4.x + f5.x) + (f6.x + f7.x));
        acc.y += ((f0.y + f1.y) + (f2.y + f3.y)) + ((f4.y + f5.y) + (f6.y + f7.y));
    }
    for (; p < pe; ++p) {
        float2 f = bf2f(hb[(size_t)srcS[p] * 64 + lane]);
        acc.x += f.x;
        acc.y += f.y;
    }
    float rd = rdeg[node];
    msgb[(size_t)node * 64 + lane] = (uint)f2bf(acc.x * rd) | ((uint)f2bf(acc.y * rd) << 16);
}

// ---------------- SAGE layer via MFMA ----------------
__global__ __launch_bounds__(256) void sage_mfma(const uint* __restrict__ hb,
                                                 const uint* __restrict__ mb,
                                                 const uint* __restrict__ Wt,
                                                 const float* __restrict__ bias,
                                                 ushort* __restrict__ outb, int N) {
    int wave = threadIdx.x >> 6, lane = threadIdx.x & 63;
    int m = lane & 15, q = lane >> 4;
    int r0 = blockIdx.x * 64 + wave * 16;
    int arow = r0 + m;
    if (arow >= N) arow = N - 1;

    f32x4 acc[8];
#pragma unroll
    for (int t = 0; t < 8; t++) acc[t] = (f32x4){0.f, 0.f, 0.f, 0.f};

    const uint* hrow = hb + (size_t)arow * 64;
    const uint* mrow = mb + (size_t)arow * 64;
#pragma unroll
    for (int sel = 0; sel < 2; sel++) {
        const uint* arowp = sel ? mrow : hrow;
        const uint* wsel = Wt + sel * 8192;
#pragma unroll
        for (int kk = 0; kk < 4; kk++) {
            int ko = kk * 16 + q * 4;
            short8 a = *(const short8*)(arowp + ko);
#pragma unroll
            for (int t = 0; t < 8; t++) {
                short8 b = *(const short8*)(wsel + (size_t)(16 * t + m) * 64 + ko);
                acc[t] = __builtin_amdgcn_mfma_f32_16x16x32_bf16(a, b, acc[t], 0, 0, 0);
            }
        }
    }

#pragma unroll
    for (int t = 0; t < 8; t++) {
        float bs = bias[16 * t + m];
#pragma unroll
        for (int r = 0; r < 4; r++) {
            int orow = r0 + q * 4 + r;
            if (orow < N) outb[(size_t)orow * 128 + 16 * t + m] = f2bf(acc[t][r] + bs);
        }
    }
}

// ---------------- edge score (unroll 8, sequential CSR-order stores, fused partials) ----------------
__global__ __launch_bounds__(256) void edge_score_csr(const uint* __restrict__ hb,
                                                      const int* __restrict__ off,
                                                      const int* __restrict__ srcS,
                                                      float* __restrict__ sc,
                                                      float2* __restrict__ pmm, int N, int E) {
    int node = blockIdx.x * 4 + (threadIdx.x >> 6);
    int lane = threadIdx.x & 63;
    float lmin = INFINITY, lmax = -INFINITY;

    if (node < N) {
        int p = off[node];
        int pe = (node == N - 1) ? E : off[node + 1];
        if (p < pe) {
            float2 d = bf2f(hb[(size_t)node * 64 + lane]);
            for (; p + 7 < pe; p += 8) {
                int s0 = srcS[p],     s1 = srcS[p + 1], s2 = srcS[p + 2], s3 = srcS[p + 3];
                int s4 = srcS[p + 4], s5 = srcS[p + 5], s6 = srcS[p + 6], s7 = srcS[p + 7];
                float2 a0 = bf2f(hb[(size_t)s0 * 64 + lane]);
                float2 a1 = bf2f(hb[(size_t)s1 * 64 + lane]);
                float2 a2 = bf2f(hb[(size_t)s2 * 64 + lane]);
                float2 a3 = bf2f(hb[(size_t)s3 * 64 + lane]);
                float2 a4 = bf2f(hb[(size_t)s4 * 64 + lane]);
                float2 a5 = bf2f(hb[(size_t)s5 * 64 + lane]);
                float2 a6 = bf2f(hb[(size_t)s6 * 64 + lane]);
                float2 a7 = bf2f(hb[(size_t)s7 * 64 + lane]);
                float v0 = a0.x * d.x + a0.y * d.y;
                float v1 = a1.x * d.x + a1.y * d.y;
                float v2 = a2.x * d.x + a2.y * d.y;
                float v3 = a3.x * d.x + a3.y * d.y;
                float v4 = a4.x * d.x + a4.y * d.y;
                float v5 = a5.x * d.x + a5.y * d.y;
                float v6 = a6.x * d.x + a6.y * d.y;
                float v7 = a7.x * d.x + a7.y * d.y;
#pragma unroll
                for (int o = 32; o > 0; o >>= 1) {
                    v0 += __shfl_down(v0, o);
                    v1 += __shfl_down(v1, o);
                    v2 += __shfl_down(v2, o);
                    v3 += __shfl_down(v3, o);
                    v4 += __shfl_down(v4, o);
                    v5 += __shfl_down(v5, o);
                    v6 += __shfl_down(v6, o);
                    v7 += __shfl_down(v7, o);
                }
                if (lane == 0) {
                    sc[p] = v0; sc[p + 1] = v1; sc[p + 2] = v2; sc[p + 3] = v3;
                    sc[p + 4] = v4; sc[p + 5] = v5; sc[p + 6] = v6; sc[p + 7] = v7;
                    float mn = fminf(fminf(fminf(v0, v1), fminf(v2, v3)),
                                     fminf(fminf(v4, v5), fminf(v6, v7)));
                    float mx = fmaxf(fmaxf(fmaxf(v0, v1), fmaxf(v2, v3)),
                                     fmaxf(fmaxf(v4, v5), fmaxf(v6, v7)));
                    lmin = fminf(lmin, mn);
                    lmax = fmaxf(lmax, mx);
                }
            }
            for (; p < pe; ++p) {
                float2 a = bf2f(hb[(size_t)srcS[p] * 64 + lane]);
                float v = a.x * d.x + a.y * d.y;
#pragma unroll
                for (int o = 32; o > 0; o >>= 1) v += __shfl_down(v, o);
                if (lane == 0) {
                    sc[p] = v;
                    lmin = fminf(lmin, v);
                    lmax = fmaxf(lmax, v);
                }
            }
        }
    }

#pragma unroll
    for (int o = 1; o <= 32; o <<= 1) {
        lmin = fminf(lmin, __shfl_xor(lmin, o));
        lmax = fmaxf(lmax, __shfl_xor(lmax, o));
    }
    __shared__ float smin[4], smax[4];
    int wv = threadIdx.x >> 6;
    if (lane == 0) { smin[wv] = lmin; smax[wv] = lmax; }
    __syncthreads();
    if (threadIdx.x == 0) {
        float m = fminf(fminf(smin[0], smin[1]), fminf(smin[2], smin[3]));
        float M = fmaxf(fmaxf(smax[0], smax[1]), fmaxf(smax[2], smax[3]));
        pmm[blockIdx.x] = make_float2(m, M);
    }
}

__global__ __launch_bounds__(1024) void minmax_final(const float2* __restrict__ pmm,
                                                     float* __restrict__ mmf, int nb) {
    float vmin = INFINITY, vmax = -INFINITY;
    for (int i = threadIdx.x; i < nb; i += 1024) {
        float2 v = pmm[i];
        vmin = fminf(vmin, v.x);
        vmax = fmaxf(vmax, v.y);
    }
#pragma unroll
    for (int o = 1; o <= 32; o <<= 1) {
        vmin = fminf(vmin, __shfl_xor(vmin, o));
        vmax = fmaxf(vmax, __shfl_xor(vmax, o));
    }
    __shared__ float smin[16], smax[16];
    int lane = threadIdx.x & 63, wv = threadIdx.x >> 6;
    if (lane == 0) { smin[wv] = vmin; smax[wv] = vmax; }
    __syncthreads();
    if (threadIdx.x == 0) {
        float m = smin[0], M = smax[0];
        for (int w = 1; w < 16; w++) { m = fminf(m, smin[w]); M = fmaxf(M, smax[w]); }
        mmf[0] = m;
        mmf[1] = M;
    }
}

// out[e] = (sc[rank[e]] - mn) * inv   (sequential rank read, L2 gather of sc)
__global__ __launch_bounds__(256) void norm_kernel(const float* __restrict__ sc,
                                                   const int* __restrict__ rank,
                                                   float* __restrict__ out,
                                                   const float* __restrict__ mmf, int E) {
    float mn = mmf[0];
    float mx = mmf[1];
    float inv = 1.0f / (mx - mn);
    int i = blockIdx.x * 256 + threadIdx.x;
    if (i < E) out[i] = (sc[rank[i]] - mn) * inv;
}

extern "C" void kernel_launch(void* const* d_in, const int* in_sizes, int n_in,
                              void* d_out, int out_size, void* d_ws, size_t ws_size,
                              hipStream_t stream) {
    const float* x   = (const float*)d_in[0];
    const int*   src = (const int*)d_in[1];
    const int*   dst = (const int*)d_in[2];
    const float* Ws1 = (const float*)d_in[3];
    const float* Wn1 = (const float*)d_in[4];
    const float* b1  = (const float*)d_in[5];
    const float* Ws2 = (const float*)d_in[6];
    const float* Wn2 = (const float*)d_in[7];
    const float* b2  = (const float*)d_in[8];

    int N = in_sizes[0] / F;   // 100000
    int E = in_sizes[1];       // 1600000
    float* out = (float*)d_out;

    int nbN = (N + 255) / 256;
    int nbE = (E + 255) / 256;
    int nbEdgeBlocks = (N + 3) / 4;       // 25000
    int NF4 = N * F / 4;

    // workspace layout (4-byte elements)
    int* off  = (int*)d_ws;                  // N
    int* cnt  = off + N;                     // N
    int* srcS = cnt + N;                     // E
    int* rank = srcS + E;                    // E
    int* relsc = rank + E;                   // E words: rel (ushort, first E/2) then sc (float, full E) — disjoint lifetimes
    ushort* rel = (ushort*)relsc;
    float* sc   = (float*)relsc;
    int* bsum = relsc + E;                   // 1024
    float* rdeg = (float*)(bsum + 1024);     // N
    float* mmf = (float*)(rdeg + N);         // 2 (+2 pad)
    float2* pmm = (float2*)(mmf + 4);        // 25600 float2
    uint* Wtb = (uint*)(pmm + 25600);        // 32768 uints
    size_t elemOff = 3 * (size_t)N + 3 * (size_t)E + 1024 + 4 + 51200 + 32768;
    elemOff = (elemOff + 3) & ~(size_t)3;    // 16B align
    uint* xb   = (uint*)d_ws + elemOff;      // N*64
    uint* msgb = xb + (size_t)N * 64;        // N*64
    uint* h1b  = msgb + (size_t)N * 64;      // N*64
    uint* h2b  = h1b + (size_t)N * 64;       // N*64

    // init
    hipMemsetAsync(cnt, 0, (size_t)N * sizeof(int), stream);

    // CSR build (by dst): one atomic pass + scan + atomic-free fill
    rank_kernel<<<nbE, 256, 0, stream>>>(dst, cnt, rel, E);
    scan_block<<<nbN, 256, 0, stream>>>(cnt, off, bsum, N);
    scan_sums<<<1, 512, 0, stream>>>(bsum, nbN);
    scan_add_rdeg<<<nbN, 256, 0, stream>>>(off, bsum, cnt, rdeg, N);
    fill_kernel<<<nbE, 256, 0, stream>>>(src, dst, off, rel, srcS, rank, E);

    // weights + input cast
    wprep<<<256, 256, 0, stream>>>(Ws1, Wn1, Ws2, Wn2, (ushort*)Wtb);
    cast_bf16<<<(NF4 + 255) / 256, 256, 0, stream>>>(x, xb, NF4);

    // layer 1
    agg_gather<<<(N + 3) / 4, 256, 0, stream>>>(xb, off, srcS, rdeg, msgb, N, E);
    sage_mfma<<<(N + 63) / 64, 256, 0, stream>>>(xb, msgb, Wtb, b1, (ushort*)h1b, N);

    // layer 2
    agg_gather<<<(N + 3) / 4, 256, 0, stream>>>(h1b, off, srcS, rdeg, msgb, N, E);
    sage_mfma<<<(N + 63) / 64, 256, 0, stream>>>(h1b, msgb, Wtb + 16384, b2, (ushort*)h2b, N);

    // edge scores (CSR order + per-block partials) + final reduce + permute-normalize
    edge_score_csr<<<nbEdgeBlocks, 256, 0, stream>>>(h2b, off, srcS, sc, pmm, N, E);
    minmax_final<<<1, 1024, 0, stream>>>(pmm, mmf, nbEdgeBlocks);
    norm_kernel<<<(E + 255) / 256, 256, 0, stream>>>(sc, rank, out, mmf, E);
}

// Round 11
// 616.541 us; speedup vs baseline: 1.4370x; 1.0995x over previous
//
#include <hip/hip_runtime.h>
#include <hip/hip_bf16.h>

#define F 128

typedef unsigned int uint;
typedef unsigned short ushort;
typedef __attribute__((ext_vector_type(8))) short short8;   // 8 bf16
typedef __attribute__((ext_vector_type(4))) float f32x4;

__device__ inline ushort f2bf(float f) {
    uint u = __float_as_uint(f);
    u += 0x7FFF + ((u >> 16) & 1);   // round-to-nearest-even
    return (ushort)(u >> 16);
}
__device__ inline float2 bf2f(uint u) {
    return make_float2(__uint_as_float(u << 16), __uint_as_float(u & 0xFFFF0000u));
}

// ---------------- CSR build ----------------
// pass 1: histogram + per-edge relative rank within its dst bucket (ONE atomic pass)
__global__ __launch_bounds__(256) void rank_kernel(const int* __restrict__ dst,
                                                   int* __restrict__ cnt,
                                                   ushort* __restrict__ rel, int E) {
    int e = blockIdx.x * 256 + threadIdx.x;
    if (e < E) rel[e] = (ushort)atomicAdd(&cnt[dst[e]], 1);
}

__global__ __launch_bounds__(256) void scan_block(const int* __restrict__ cnt,
                                                  int* __restrict__ off,
                                                  int* __restrict__ bsum, int N) {
    __shared__ int t[256];
    int i = blockIdx.x * 256 + threadIdx.x;
    int v = (i < N) ? cnt[i] : 0;
    t[threadIdx.x] = v;
    __syncthreads();
    for (int o = 1; o < 256; o <<= 1) {
        int x = (threadIdx.x >= o) ? t[threadIdx.x - o] : 0;
        __syncthreads();
        t[threadIdx.x] += x;
        __syncthreads();
    }
    if (i < N) off[i] = t[threadIdx.x] - v;
    if (threadIdx.x == 255) bsum[blockIdx.x] = t[255];
}

__global__ __launch_bounds__(512) void scan_sums(int* __restrict__ bsum, int nb) {
    __shared__ int t[512];
    int v = (threadIdx.x < nb) ? bsum[threadIdx.x] : 0;
    t[threadIdx.x] = v;
    __syncthreads();
    for (int o = 1; o < 512; o <<= 1) {
        int x = (threadIdx.x >= o) ? t[threadIdx.x - o] : 0;
        __syncthreads();
        t[threadIdx.x] += x;
        __syncthreads();
    }
    if (threadIdx.x < nb) bsum[threadIdx.x] = t[threadIdx.x] - v;
}

// finalize offsets + rdeg
__global__ __launch_bounds__(256) void scan_add_rdeg(int* __restrict__ off,
                                                     const int* __restrict__ bsum,
                                                     const int* __restrict__ cnt,
                                                     float* __restrict__ rdeg, int N) {
    int i = blockIdx.x * 256 + threadIdx.x;
    if (i >= N) return;
    off[i] += bsum[blockIdx.x];
    rdeg[i] = 1.0f / fmaxf((float)cnt[i], 1.0f);
}

// pass 2: atomic-free fill. p derived from scan + relative rank.
__global__ __launch_bounds__(256) void fill_kernel(const int* __restrict__ src,
                                                   const int* __restrict__ dst,
                                                   const int* __restrict__ off,
                                                   const ushort* __restrict__ rel,
                                                   int* __restrict__ srcS,
                                                   int* __restrict__ rank, int E) {
    int e = blockIdx.x * 256 + threadIdx.x;
    if (e >= E) return;
    int p = off[dst[e]] + (int)rel[e];
    srcS[p] = src[e];
    rank[e] = p;
}

// ---------------- weight prep: cast + transpose 4 matrices [k][n] -> bf16 [n][k] ----------------
__global__ __launch_bounds__(256) void wprep(const float* __restrict__ W0,
                                             const float* __restrict__ W1,
                                             const float* __restrict__ W2,
                                             const float* __restrict__ W3,
                                             ushort* __restrict__ Wt) {
    int idx = blockIdx.x * 256 + threadIdx.x;   // 4 * 128*128
    if (idx >= 4 * 16384) return;
    int mat = idx >> 14;
    int pos = idx & 16383;
    int k = pos >> 7, n = pos & 127;
    const float* W = (mat == 0) ? W0 : (mat == 1) ? W1 : (mat == 2) ? W2 : W3;
    Wt[mat * 16384 + n * 128 + k] = f2bf(W[k * 128 + n]);
}

// ---------------- f32 -> bf16 cast (x only) ----------------
__global__ __launch_bounds__(256) void cast_bf16(const float* __restrict__ in,
                                                 uint* __restrict__ outb, int n4) {
    int i = blockIdx.x * 256 + threadIdx.x;
    if (i >= n4) return;
    float4 v = ((const float4*)in)[i];
    uint ua = (uint)f2bf(v.x) | ((uint)f2bf(v.y) << 16);
    uint ub = (uint)f2bf(v.z) | ((uint)f2bf(v.w) << 16);
    ((uint2*)outb)[i] = make_uint2(ua, ub);
}

// ---------------- aggregate (gather, unroll 8): msg[n] = mean h[srcs] ----------------
// wave per node, lane = feature pair; p wave-uniform -> coalesced row loads.
__global__ __launch_bounds__(256) void agg_gather(const uint* __restrict__ hb,
                                                  const int* __restrict__ off,
                                                  const int* __restrict__ srcS,
                                                  const float* __restrict__ rdeg,
                                                  uint* __restrict__ msgb, int N, int E) {
    int node = blockIdx.x * 4 + (threadIdx.x >> 6);
    int lane = threadIdx.x & 63;
    if (node >= N) return;
    int p = off[node];
    int pe = (node == N - 1) ? E : off[node + 1];
    float2 acc = make_float2(0.f, 0.f);
    for (; p + 7 < pe; p += 8) {
        int s0 = srcS[p],     s1 = srcS[p + 1], s2 = srcS[p + 2], s3 = srcS[p + 3];
        int s4 = srcS[p + 4], s5 = srcS[p + 5], s6 = srcS[p + 6], s7 = srcS[p + 7];
        float2 f0 = bf2f(hb[(size_t)s0 * 64 + lane]);
        float2 f1 = bf2f(hb[(size_t)s1 * 64 + lane]);
        float2 f2 = bf2f(hb[(size_t)s2 * 64 + lane]);
        float2 f3 = bf2f(hb[(size_t)s3 * 64 + lane]);
        float2 f4 = bf2f(hb[(size_t)s4 * 64 + lane]);
        float2 f5 = bf2f(hb[(size_t)s5 * 64 + lane]);
        float2 f6 = bf2f(hb[(size_t)s6 * 64 + lane]);
        float2 f7 = bf2f(hb[(size_t)s7 * 64 + lane]);
        acc.x += ((f0.x + f1.x) + (f2.x + f3.x)) + ((f4.x + f5.x) + (f6.x + f7.x));
        acc.y += ((f0.y + f1.y) + (f2.y + f3.y)) + ((f4.y + f5.y) + (f6.y + f7.y));
    }
    for (; p < pe; ++p) {
        float2 f = bf2f(hb[(size_t)srcS[p] * 64 + lane]);
        acc.x += f.x;
        acc.y += f.y;
    }
    float rd = rdeg[node];
    msgb[(size_t)node * 64 + lane] = (uint)f2bf(acc.x * rd) | ((uint)f2bf(acc.y * rd) << 16);
}

// ---------------- SAGE layer via MFMA ----------------
__global__ __launch_bounds__(256) void sage_mfma(const uint* __restrict__ hb,
                                                 const uint* __restrict__ mb,
                                                 const uint* __restrict__ Wt,
                                                 const float* __restrict__ bias,
                                                 ushort* __restrict__ outb, int N) {
    int wave = threadIdx.x >> 6, lane = threadIdx.x & 63;
    int m = lane & 15, q = lane >> 4;
    int r0 = blockIdx.x * 64 + wave * 16;
    int arow = r0 + m;
    if (arow >= N) arow = N - 1;

    f32x4 acc[8];
#pragma unroll
    for (int t = 0; t < 8; t++) acc[t] = (f32x4){0.f, 0.f, 0.f, 0.f};

    const uint* hrow = hb + (size_t)arow * 64;
    const uint* mrow = mb + (size_t)arow * 64;
#pragma unroll
    for (int sel = 0; sel < 2; sel++) {
        const uint* arowp = sel ? mrow : hrow;
        const uint* wsel = Wt + sel * 8192;
#pragma unroll
        for (int kk = 0; kk < 4; kk++) {
            int ko = kk * 16 + q * 4;
            short8 a = *(const short8*)(arowp + ko);
#pragma unroll
            for (int t = 0; t < 8; t++) {
                short8 b = *(const short8*)(wsel + (size_t)(16 * t + m) * 64 + ko);
                acc[t] = __builtin_amdgcn_mfma_f32_16x16x32_bf16(a, b, acc[t], 0, 0, 0);
            }
        }
    }

#pragma unroll
    for (int t = 0; t < 8; t++) {
        float bs = bias[16 * t + m];
#pragma unroll
        for (int r = 0; r < 4; r++) {
            int orow = r0 + q * 4 + r;
            if (orow < N) outb[(size_t)orow * 128 + 16 * t + m] = f2bf(acc[t][r] + bs);
        }
    }
}

// ---------------- edge score via MFMA matrix-vector: 16 edges per batch ----------------
// Wave per node. A = 16 gathered src rows (lane m -> row srcS[p+m]); B = node row
// broadcast to all 16 cols; D[i][j] = dot(h[src_i], h[node]) identical over j.
// Col-0 lanes (m==0) store float4 -> sc[p + q*4] (sequential CSR order).
__global__ __launch_bounds__(256) void edge_score_mfma(const uint* __restrict__ hb,
                                                       const int* __restrict__ off,
                                                       const int* __restrict__ srcS,
                                                       float* __restrict__ sc,
                                                       float2* __restrict__ pmm, int N, int E) {
    int node = blockIdx.x * 4 + (threadIdx.x >> 6);
    int lane = threadIdx.x & 63;
    int m = lane & 15, q = lane >> 4;
    float lmin = INFINITY, lmax = -INFINITY;

    if (node < N) {
        int p = off[node];
        int pe = (node == N - 1) ? E : off[node + 1];
        if (p < pe) {
            const uint* nrow = hb + (size_t)node * 64;
            short8 bfr[4];
#pragma unroll
            for (int kk = 0; kk < 4; kk++)
                bfr[kk] = *(const short8*)(nrow + kk * 16 + q * 4);   // B[k][n]=h_node[k] ∀n

            for (; p < pe; p += 16) {
                int idx = p + m;
                if (idx >= pe) idx = pe - 1;                  // clamp: dup rows, stores masked
                const uint* arow = hb + (size_t)srcS[idx] * 64;
                f32x4 acc = (f32x4){0.f, 0.f, 0.f, 0.f};
#pragma unroll
                for (int kk = 0; kk < 4; kk++) {
                    short8 a = *(const short8*)(arow + kk * 16 + q * 4);
                    acc = __builtin_amdgcn_mfma_f32_16x16x32_bf16(a, bfr[kk], acc, 0, 0, 0);
                }
                // D: col=lane&15, row=q*4+r (cols identical) -> col-0 lanes own edges q*4..q*4+3
                if (m == 0) {
                    if (p + 16 <= pe) {
                        *(float4*)(sc + p + q * 4) = make_float4(acc[0], acc[1], acc[2], acc[3]);
                        float mn = fminf(fminf(acc[0], acc[1]), fminf(acc[2], acc[3]));
                        float mx = fmaxf(fmaxf(acc[0], acc[1]), fmaxf(acc[2], acc[3]));
                        lmin = fminf(lmin, mn);
                        lmax = fmaxf(lmax, mx);
                    } else {
#pragma unroll
                        for (int r = 0; r < 4; r++) {
                            int e = p + q * 4 + r;
                            if (e < pe) {
                                sc[e] = acc[r];
                                lmin = fminf(lmin, acc[r]);
                                lmax = fmaxf(lmax, acc[r]);
                            }
                        }
                    }
                }
            }
        }
    }

    // block-level min/max partials (non-atomic)
#pragma unroll
    for (int o = 1; o <= 32; o <<= 1) {
        lmin = fminf(lmin, __shfl_xor(lmin, o));
        lmax = fmaxf(lmax, __shfl_xor(lmax, o));
    }
    __shared__ float smin[4], smax[4];
    int wv = threadIdx.x >> 6;
    if (lane == 0) { smin[wv] = lmin; smax[wv] = lmax; }
    __syncthreads();
    if (threadIdx.x == 0) {
        float mA = fminf(fminf(smin[0], smin[1]), fminf(smin[2], smin[3]));
        float MA = fmaxf(fmaxf(smax[0], smax[1]), fmaxf(smax[2], smax[3]));
        pmm[blockIdx.x] = make_float2(mA, MA);
    }
}

__global__ __launch_bounds__(1024) void minmax_final(const float2* __restrict__ pmm,
                                                     float* __restrict__ mmf, int nb) {
    float vmin = INFINITY, vmax = -INFINITY;
    for (int i = threadIdx.x; i < nb; i += 1024) {
        float2 v = pmm[i];
        vmin = fminf(vmin, v.x);
        vmax = fmaxf(vmax, v.y);
    }
#pragma unroll
    for (int o = 1; o <= 32; o <<= 1) {
        vmin = fminf(vmin, __shfl_xor(vmin, o));
        vmax = fmaxf(vmax, __shfl_xor(vmax, o));
    }
    __shared__ float smin[16], smax[16];
    int lane = threadIdx.x & 63, wv = threadIdx.x >> 6;
    if (lane == 0) { smin[wv] = vmin; smax[wv] = vmax; }
    __syncthreads();
    if (threadIdx.x == 0) {
        float m = smin[0], M = smax[0];
        for (int w = 1; w < 16; w++) { m = fminf(m, smin[w]); M = fmaxf(M, smax[w]); }
        mmf[0] = m;
        mmf[1] = M;
    }
}

// out[e] = (sc[rank[e]] - mn) * inv   (sequential rank read, L2 gather of sc)
__global__ __launch_bounds__(256) void norm_kernel(const float* __restrict__ sc,
                                                   const int* __restrict__ rank,
                                                   float* __restrict__ out,
                                                   const float* __restrict__ mmf, int E) {
    float mn = mmf[0];
    float mx = mmf[1];
    float inv = 1.0f / (mx - mn);
    int i = blockIdx.x * 256 + threadIdx.x;
    if (i < E) out[i] = (sc[rank[i]] - mn) * inv;
}

extern "C" void kernel_launch(void* const* d_in, const int* in_sizes, int n_in,
                              void* d_out, int out_size, void* d_ws, size_t ws_size,
                              hipStream_t stream) {
    const float* x   = (const float*)d_in[0];
    const int*   src = (const int*)d_in[1];
    const int*   dst = (const int*)d_in[2];
    const float* Ws1 = (const float*)d_in[3];
    const float* Wn1 = (const float*)d_in[4];
    const float* b1  = (const float*)d_in[5];
    const float* Ws2 = (const float*)d_in[6];
    const float* Wn2 = (const float*)d_in[7];
    const float* b2  = (const float*)d_in[8];

    int N = in_sizes[0] / F;   // 100000
    int E = in_sizes[1];       // 1600000
    float* out = (float*)d_out;

    int nbN = (N + 255) / 256;
    int nbE = (E + 255) / 256;
    int nbEdgeBlocks = (N + 3) / 4;       // 25000
    int NF4 = N * F / 4;

    // workspace layout (4-byte elements)
    int* off  = (int*)d_ws;                  // N
    int* cnt  = off + N;                     // N
    int* srcS = cnt + N;                     // E
    int* rank = srcS + E;                    // E
    int* relsc = rank + E;                   // E words: rel (ushort) then sc (float) — disjoint lifetimes
    ushort* rel = (ushort*)relsc;
    float* sc   = (float*)relsc;
    int* bsum = relsc + E;                   // 1024
    float* rdeg = (float*)(bsum + 1024);     // N
    float* mmf = (float*)(rdeg + N);         // 2 (+2 pad)
    float2* pmm = (float2*)(mmf + 4);        // 25600 float2
    uint* Wtb = (uint*)(pmm + 25600);        // 32768 uints
    size_t elemOff = 3 * (size_t)N + 3 * (size_t)E + 1024 + 4 + 51200 + 32768;
    elemOff = (elemOff + 3) & ~(size_t)3;    // 16B align
    uint* xb   = (uint*)d_ws + elemOff;      // N*64
    uint* msgb = xb + (size_t)N * 64;        // N*64
    uint* h1b  = msgb + (size_t)N * 64;      // N*64
    uint* h2b  = h1b + (size_t)N * 64;       // N*64

    // init
    hipMemsetAsync(cnt, 0, (size_t)N * sizeof(int), stream);

    // CSR build (by dst): one atomic pass + scan + atomic-free fill
    rank_kernel<<<nbE, 256, 0, stream>>>(dst, cnt, rel, E);
    scan_block<<<nbN, 256, 0, stream>>>(cnt, off, bsum, N);
    scan_sums<<<1, 512, 0, stream>>>(bsum, nbN);
    scan_add_rdeg<<<nbN, 256, 0, stream>>>(off, bsum, cnt, rdeg, N);
    fill_kernel<<<nbE, 256, 0, stream>>>(src, dst, off, rel, srcS, rank, E);

    // weights + input cast
    wprep<<<256, 256, 0, stream>>>(Ws1, Wn1, Ws2, Wn2, (ushort*)Wtb);
    cast_bf16<<<(NF4 + 255) / 256, 256, 0, stream>>>(x, xb, NF4);

    // layer 1
    agg_gather<<<(N + 3) / 4, 256, 0, stream>>>(xb, off, srcS, rdeg, msgb, N, E);
    sage_mfma<<<(N + 63) / 64, 256, 0, stream>>>(xb, msgb, Wtb, b1, (ushort*)h1b, N);

    // layer 2
    agg_gather<<<(N + 3) / 4, 256, 0, stream>>>(h1b, off, srcS, rdeg, msgb, N, E);
    sage_mfma<<<(N + 63) / 64, 256, 0, stream>>>(h1b, msgb, Wtb + 16384, b2, (ushort*)h2b, N);

    // edge scores via MFMA (CSR order + per-block partials) + final reduce + permute-normalize
    edge_score_mfma<<<nbEdgeBlocks, 256, 0, stream>>>(h2b, off, srcS, sc, pmm, N, E);
    minmax_final<<<1, 1024, 0, stream>>>(pmm, mmf, nbEdgeBlocks);
    norm_kernel<<<(E + 255) / 256, 256, 0, stream>>>(sc, rank, out, mmf, E);
}

// Round 12
// 604.045 us; speedup vs baseline: 1.4668x; 1.0207x over previous
//
#include <hip/hip_runtime.h>
#include <hip/hip_bf16.h>

#define F 128

typedef unsigned int uint;
typedef unsigned short ushort;
typedef __attribute__((ext_vector_type(8))) short short8;   // 8 bf16
typedef __attribute__((ext_vector_type(4))) float f32x4;

__device__ inline ushort f2bf(float f) {
    uint u = __float_as_uint(f);
    u += 0x7FFF + ((u >> 16) & 1);   // round-to-nearest-even
    return (ushort)(u >> 16);
}
__device__ inline float2 bf2f(uint u) {
    return make_float2(__uint_as_float(u << 16), __uint_as_float(u & 0xFFFF0000u));
}

// ---------------- CSR build ----------------
// pass 1: histogram + per-edge relative rank within its dst bucket (ONE atomic pass)
__global__ __launch_bounds__(256) void rank_kernel(const int* __restrict__ dst,
                                                   int* __restrict__ cnt,
                                                   ushort* __restrict__ rel, int E) {
    int e = blockIdx.x * 256 + threadIdx.x;
    if (e < E) rel[e] = (ushort)atomicAdd(&cnt[dst[e]], 1);
}

__global__ __launch_bounds__(256) void scan_block(const int* __restrict__ cnt,
                                                  int* __restrict__ off,
                                                  int* __restrict__ bsum, int N) {
    __shared__ int t[256];
    int i = blockIdx.x * 256 + threadIdx.x;
    int v = (i < N) ? cnt[i] : 0;
    t[threadIdx.x] = v;
    __syncthreads();
    for (int o = 1; o < 256; o <<= 1) {
        int x = (threadIdx.x >= o) ? t[threadIdx.x - o] : 0;
        __syncthreads();
        t[threadIdx.x] += x;
        __syncthreads();
    }
    if (i < N) off[i] = t[threadIdx.x] - v;
    if (threadIdx.x == 255) bsum[blockIdx.x] = t[255];
}

__global__ __launch_bounds__(512) void scan_sums(int* __restrict__ bsum, int nb) {
    __shared__ int t[512];
    int v = (threadIdx.x < nb) ? bsum[threadIdx.x] : 0;
    t[threadIdx.x] = v;
    __syncthreads();
    for (int o = 1; o < 512; o <<= 1) {
        int x = (threadIdx.x >= o) ? t[threadIdx.x - o] : 0;
        __syncthreads();
        t[threadIdx.x] += x;
        __syncthreads();
    }
    if (threadIdx.x < nb) bsum[threadIdx.x] = t[threadIdx.x] - v;
}

// finalize offsets + rdeg
__global__ __launch_bounds__(256) void scan_add_rdeg(int* __restrict__ off,
                                                     const int* __restrict__ bsum,
                                                     const int* __restrict__ cnt,
                                                     float* __restrict__ rdeg, int N) {
    int i = blockIdx.x * 256 + threadIdx.x;
    if (i >= N) return;
    off[i] += bsum[blockIdx.x];
    rdeg[i] = 1.0f / fmaxf((float)cnt[i], 1.0f);
}

// pass 2: atomic-free fill (no rank store; norm recomputes it)
__global__ __launch_bounds__(256) void fill_kernel(const int* __restrict__ src,
                                                   const int* __restrict__ dst,
                                                   const int* __restrict__ off,
                                                   const ushort* __restrict__ rel,
                                                   int* __restrict__ srcS, int E) {
    int e = blockIdx.x * 256 + threadIdx.x;
    if (e >= E) return;
    srcS[off[dst[e]] + (int)rel[e]] = src[e];
}

// ---------------- fused prep: cast x -> bf16 rows, plus weight cast+transpose ----------------
// idx < NF4: cast 4 floats of x; else: one weight element of the 4 matrices.
__global__ __launch_bounds__(256) void prep_kernel(const float* __restrict__ x,
                                                   const float* __restrict__ W0,
                                                   const float* __restrict__ W1,
                                                   const float* __restrict__ W2,
                                                   const float* __restrict__ W3,
                                                   uint* __restrict__ xb,
                                                   ushort* __restrict__ Wt, int NF4) {
    int i = blockIdx.x * 256 + threadIdx.x;
    if (i < NF4) {
        float4 v = ((const float4*)x)[i];
        uint ua = (uint)f2bf(v.x) | ((uint)f2bf(v.y) << 16);
        uint ub = (uint)f2bf(v.z) | ((uint)f2bf(v.w) << 16);
        ((uint2*)xb)[i] = make_uint2(ua, ub);
    } else {
        int idx = i - NF4;
        if (idx >= 4 * 16384) return;
        int mat = idx >> 14;
        int pos = idx & 16383;
        int k = pos >> 7, n = pos & 127;
        const float* W = (mat == 0) ? W0 : (mat == 1) ? W1 : (mat == 2) ? W2 : W3;
        Wt[mat * 16384 + n * 128 + k] = f2bf(W[k * 128 + n]);
    }
}

// ---------------- aggregate (gather, rounded-up unroll 8, no serial tail) ----------------
// wave per node, lane = feature pair; indices wave-uniform (scalar loads).
// Loop rounds deg up to a multiple of 8 with idx clamped to last; the d duplicate
// adds of row[last] are subtracted afterwards (one extra coalesced load + 2 FMA).
__global__ __launch_bounds__(256) void agg_gather(const uint* __restrict__ hb,
                                                  const int* __restrict__ off,
                                                  const int* __restrict__ srcS,
                                                  const float* __restrict__ rdeg,
                                                  uint* __restrict__ msgb, int N, int E) {
    int node = blockIdx.x * 4 + (threadIdx.x >> 6);
    int lane = threadIdx.x & 63;
    if (node >= N) return;
    int p = off[node];
    int pe = (node == N - 1) ? E : off[node + 1];
    float2 acc = make_float2(0.f, 0.f);
    if (p < pe) {
        int deg = pe - p;
        int last = pe - 1;
        for (; p < pe; p += 8) {
            int i0 = min(p + 0, last), i1 = min(p + 1, last);
            int i2 = min(p + 2, last), i3 = min(p + 3, last);
            int i4 = min(p + 4, last), i5 = min(p + 5, last);
            int i6 = min(p + 6, last), i7 = min(p + 7, last);
            int s0 = srcS[i0], s1 = srcS[i1], s2 = srcS[i2], s3 = srcS[i3];
            int s4 = srcS[i4], s5 = srcS[i5], s6 = srcS[i6], s7 = srcS[i7];
            float2 f0 = bf2f(hb[(size_t)s0 * 64 + lane]);
            float2 f1 = bf2f(hb[(size_t)s1 * 64 + lane]);
            float2 f2 = bf2f(hb[(size_t)s2 * 64 + lane]);
            float2 f3 = bf2f(hb[(size_t)s3 * 64 + lane]);
            float2 f4 = bf2f(hb[(size_t)s4 * 64 + lane]);
            float2 f5 = bf2f(hb[(size_t)s5 * 64 + lane]);
            float2 f6 = bf2f(hb[(size_t)s6 * 64 + lane]);
            float2 f7 = bf2f(hb[(size_t)s7 * 64 + lane]);
            acc.x += ((f0.x + f1.x) + (f2.x + f3.x)) + ((f4.x + f5.x) + (f6.x + f7.x));
            acc.y += ((f0.y + f1.y) + (f2.y + f3.y)) + ((f4.y + f5.y) + (f6.y + f7.y));
        }
        int d = (8 - (deg & 7)) & 7;          // duplicate count of row[last]
        if (d) {
            float2 fl = bf2f(hb[(size_t)srcS[last] * 64 + lane]);
            float fd = (float)d;
            acc.x -= fd * fl.x;
            acc.y -= fd * fl.y;
        }
    }
    float rd = rdeg[node];
    msgb[(size_t)node * 64 + lane] = (uint)f2bf(acc.x * rd) | ((uint)f2bf(acc.y * rd) << 16);
}

// ---------------- SAGE layer via MFMA ----------------
__global__ __launch_bounds__(256) void sage_mfma(const uint* __restrict__ hb,
                                                 const uint* __restrict__ mb,
                                                 const uint* __restrict__ Wt,
                                                 const float* __restrict__ bias,
                                                 ushort* __restrict__ outb, int N) {
    int wave = threadIdx.x >> 6, lane = threadIdx.x & 63;
    int m = lane & 15, q = lane >> 4;
    int r0 = blockIdx.x * 64 + wave * 16;
    int arow = r0 + m;
    if (arow >= N) arow = N - 1;

    f32x4 acc[8];
#pragma unroll
    for (int t = 0; t < 8; t++) acc[t] = (f32x4){0.f, 0.f, 0.f, 0.f};

    const uint* hrow = hb + (size_t)arow * 64;
    const uint* mrow = mb + (size_t)arow * 64;
#pragma unroll
    for (int sel = 0; sel < 2; sel++) {
        const uint* arowp = sel ? mrow : hrow;
        const uint* wsel = Wt + sel * 8192;
#pragma unroll
        for (int kk = 0; kk < 4; kk++) {
            int ko = kk * 16 + q * 4;
            short8 a = *(const short8*)(arowp + ko);
#pragma unroll
            for (int t = 0; t < 8; t++) {
                short8 b = *(const short8*)(wsel + (size_t)(16 * t + m) * 64 + ko);
                acc[t] = __builtin_amdgcn_mfma_f32_16x16x32_bf16(a, b, acc[t], 0, 0, 0);
            }
        }
    }

#pragma unroll
    for (int t = 0; t < 8; t++) {
        float bs = bias[16 * t + m];
#pragma unroll
        for (int r = 0; r < 4; r++) {
            int orow = r0 + q * 4 + r;
            if (orow < N) outb[(size_t)orow * 128 + 16 * t + m] = f2bf(acc[t][r] + bs);
        }
    }
}

// ---------------- edge score via MFMA matrix-vector: 16 edges per batch ----------------
__global__ __launch_bounds__(256) void edge_score_mfma(const uint* __restrict__ hb,
                                                       const int* __restrict__ off,
                                                       const int* __restrict__ srcS,
                                                       float* __restrict__ sc,
                                                       float2* __restrict__ pmm, int N, int E) {
    int node = blockIdx.x * 4 + (threadIdx.x >> 6);
    int lane = threadIdx.x & 63;
    int m = lane & 15, q = lane >> 4;
    float lmin = INFINITY, lmax = -INFINITY;

    if (node < N) {
        int p = off[node];
        int pe = (node == N - 1) ? E : off[node + 1];
        if (p < pe) {
            const uint* nrow = hb + (size_t)node * 64;
            short8 bfr[4];
#pragma unroll
            for (int kk = 0; kk < 4; kk++)
                bfr[kk] = *(const short8*)(nrow + kk * 16 + q * 4);   // B[k][n]=h_node[k] ∀n

            for (; p < pe; p += 16) {
                int idx = p + m;
                if (idx >= pe) idx = pe - 1;                  // clamp: dup rows, stores masked
                const uint* arow = hb + (size_t)srcS[idx] * 64;
                f32x4 acc = (f32x4){0.f, 0.f, 0.f, 0.f};
#pragma unroll
                for (int kk = 0; kk < 4; kk++) {
                    short8 a = *(const short8*)(arow + kk * 16 + q * 4);
                    acc = __builtin_amdgcn_mfma_f32_16x16x32_bf16(a, bfr[kk], acc, 0, 0, 0);
                }
                // D: col=lane&15, row=q*4+r (cols identical) -> col-0 lanes own edges q*4..q*4+3
                if (m == 0) {
                    if (p + 16 <= pe) {
                        *(float4*)(sc + p + q * 4) = make_float4(acc[0], acc[1], acc[2], acc[3]);
                        float mn = fminf(fminf(acc[0], acc[1]), fminf(acc[2], acc[3]));
                        float mx = fmaxf(fmaxf(acc[0], acc[1]), fmaxf(acc[2], acc[3]));
                        lmin = fminf(lmin, mn);
                        lmax = fmaxf(lmax, mx);
                    } else {
#pragma unroll
                        for (int r = 0; r < 4; r++) {
                            int e = p + q * 4 + r;
                            if (e < pe) {
                                sc[e] = acc[r];
                                lmin = fminf(lmin, acc[r]);
                                lmax = fmaxf(lmax, acc[r]);
                            }
                        }
                    }
                }
            }
        }
    }

#pragma unroll
    for (int o = 1; o <= 32; o <<= 1) {
        lmin = fminf(lmin, __shfl_xor(lmin, o));
        lmax = fmaxf(lmax, __shfl_xor(lmax, o));
    }
    __shared__ float smin[4], smax[4];
    int wv = threadIdx.x >> 6;
    if (lane == 0) { smin[wv] = lmin; smax[wv] = lmax; }
    __syncthreads();
    if (threadIdx.x == 0) {
        float mA = fminf(fminf(smin[0], smin[1]), fminf(smin[2], smin[3]));
        float MA = fmaxf(fmaxf(smax[0], smax[1]), fmaxf(smax[2], smax[3]));
        pmm[blockIdx.x] = make_float2(mA, MA);
    }
}

__global__ __launch_bounds__(1024) void minmax_final(const float2* __restrict__ pmm,
                                                     float* __restrict__ mmf, int nb) {
    float vmin = INFINITY, vmax = -INFINITY;
    for (int i = threadIdx.x; i < nb; i += 1024) {
        float2 v = pmm[i];
        vmin = fminf(vmin, v.x);
        vmax = fmaxf(vmax, v.y);
    }
#pragma unroll
    for (int o = 1; o <= 32; o <<= 1) {
        vmin = fminf(vmin, __shfl_xor(vmin, o));
        vmax = fmaxf(vmax, __shfl_xor(vmax, o));
    }
    __shared__ float smin[16], smax[16];
    int lane = threadIdx.x & 63, wv = threadIdx.x >> 6;
    if (lane == 0) { smin[wv] = vmin; smax[wv] = vmax; }
    __syncthreads();
    if (threadIdx.x == 0) {
        float m = smin[0], M = smax[0];
        for (int w = 1; w < 16; w++) { m = fminf(m, smin[w]); M = fmaxf(M, smax[w]); }
        mmf[0] = m;
        mmf[1] = M;
    }
}

// out[e] = (sc[off[dst[e]] + rel[e]] - mn) * inv
__global__ __launch_bounds__(256) void norm_kernel(const float* __restrict__ sc,
                                                   const int* __restrict__ dst,
                                                   const ushort* __restrict__ rel,
                                                   const int* __restrict__ off,
                                                   float* __restrict__ out,
                                                   const float* __restrict__ mmf, int E) {
    float mn = mmf[0];
    float mx = mmf[1];
    float inv = 1.0f / (mx - mn);
    int i = blockIdx.x * 256 + threadIdx.x;
    if (i < E) {
        int p = off[dst[i]] + (int)rel[i];
        out[i] = (sc[p] - mn) * inv;
    }
}

extern "C" void kernel_launch(void* const* d_in, const int* in_sizes, int n_in,
                              void* d_out, int out_size, void* d_ws, size_t ws_size,
                              hipStream_t stream) {
    const float* x   = (const float*)d_in[0];
    const int*   src = (const int*)d_in[1];
    const int*   dst = (const int*)d_in[2];
    const float* Ws1 = (const float*)d_in[3];
    const float* Wn1 = (const float*)d_in[4];
    const float* b1  = (const float*)d_in[5];
    const float* Ws2 = (const float*)d_in[6];
    const float* Wn2 = (const float*)d_in[7];
    const float* b2  = (const float*)d_in[8];

    int N = in_sizes[0] / F;   // 100000
    int E = in_sizes[1];       // 1600000
    float* out = (float*)d_out;

    int nbN = (N + 255) / 256;
    int nbE = (E + 255) / 256;
    int nbEdgeBlocks = (N + 3) / 4;       // 25000
    int NF4 = N * F / 4;

    // workspace layout (4-byte elements)
    int* off  = (int*)d_ws;                  // N
    int* cnt  = off + N;                     // N
    int* srcS = cnt + N;                     // E
    ushort* rel = (ushort*)(srcS + E);       // E ushorts = E/2 words
    float* sc = (float*)((int*)rel + E / 2); // E
    int* bsum = (int*)(sc + E);              // 1024
    float* rdeg = (float*)(bsum + 1024);     // N
    float* mmf = (float*)(rdeg + N);         // 2 (+2 pad)
    float2* pmm = (float2*)(mmf + 4);        // 25600 float2
    uint* Wtb = (uint*)(pmm + 25600);        // 32768 uints
    size_t elemOff = 3 * (size_t)N + 2 * (size_t)E + (size_t)E / 2 + 1024 + 4 + 51200 + 32768;
    elemOff = (elemOff + 3) & ~(size_t)3;    // 16B align
    uint* xb   = (uint*)d_ws + elemOff;      // N*64
    uint* msgb = xb + (size_t)N * 64;        // N*64
    uint* h1b  = msgb + (size_t)N * 64;      // N*64
    uint* h2b  = h1b + (size_t)N * 64;       // N*64

    // init
    hipMemsetAsync(cnt, 0, (size_t)N * sizeof(int), stream);

    // CSR build (by dst): one atomic pass + scan + atomic-free fill
    rank_kernel<<<nbE, 256, 0, stream>>>(dst, cnt, rel, E);
    scan_block<<<nbN, 256, 0, stream>>>(cnt, off, bsum, N);
    scan_sums<<<1, 512, 0, stream>>>(bsum, nbN);
    scan_add_rdeg<<<nbN, 256, 0, stream>>>(off, bsum, cnt, rdeg, N);
    fill_kernel<<<nbE, 256, 0, stream>>>(src, dst, off, rel, srcS, E);

    // fused weights + input cast
    prep_kernel<<<(NF4 + 4 * 16384 + 255) / 256, 256, 0, stream>>>(
        x, Ws1, Wn1, Ws2, Wn2, xb, (ushort*)Wtb, NF4);

    // layer 1
    agg_gather<<<(N + 3) / 4, 256, 0, stream>>>(xb, off, srcS, rdeg, msgb, N, E);
    sage_mfma<<<(N + 63) / 64, 256, 0, stream>>>(xb, msgb, Wtb, b1, (ushort*)h1b, N);

    // layer 2
    agg_gather<<<(N + 3) / 4, 256, 0, stream>>>(h1b, off, srcS, rdeg, msgb, N, E);
    sage_mfma<<<(N + 63) / 64, 256, 0, stream>>>(h1b, msgb, Wtb + 16384, b2, (ushort*)h2b, N);

    // edge scores via MFMA (CSR order + per-block partials) + final reduce + permute-normalize
    edge_score_mfma<<<nbEdgeBlocks, 256, 0, stream>>>(h2b, off, srcS, sc, pmm, N, E);
    minmax_final<<<1, 1024, 0, stream>>>(pmm, mmf, nbEdgeBlocks);
    norm_kernel<<<(E + 255) / 256, 256, 0, stream>>>(sc, dst, rel, off, out, mmf, E);
}